// Round 2
// 224.091 us; speedup vs baseline: 1.0192x; 1.0192x over previous
//
#include <hip/hip_runtime.h>
#include <math.h>

typedef __bf16 bf16x8 __attribute__((ext_vector_type(8)));
typedef float  f32x4  __attribute__((ext_vector_type(4)));
typedef unsigned short us4 __attribute__((ext_vector_type(4)));

constexpr int N_EMBD = 1024;
constexpr int T_SEQ  = 128;
constexpr int HS     = 128;
constexpr int BATCH  = 256;
constexpr int ROWS   = BATCH * T_SEQ;   // 32768

__device__ __forceinline__ void async16(const void* g, void* l) {
    __builtin_amdgcn_global_load_lds(
        (const __attribute__((address_space(1))) unsigned int*)g,
        (__attribute__((address_space(3))) unsigned int*)l, 16, 0, 0);
}
__device__ __forceinline__ unsigned short bfbits(float f) {
    return __builtin_bit_cast(unsigned short, (__bf16)f);
}
__device__ __forceinline__ f32x4 zero4() {
    f32x4 z = {0.f, 0.f, 0.f, 0.f};
    return z;
}

// ---------------- Kernel 0: W cast + transpose ----------------
// Wt[nt*128 + n][k] = W_nt[k][n] as bf16.  48 blocks = 3 nt x 16 k-chunks.
__global__ __launch_bounds__(256) void wcast(
    const float* __restrict__ Wq, const float* __restrict__ Wk,
    const float* __restrict__ Wv, unsigned short* __restrict__ Wt)
{
    __shared__ unsigned short tile[64][130];
    const int bid = blockIdx.x;
    const int nt  = bid >> 4;
    const int k0  = (bid & 15) << 6;
    const float* src = (nt == 0) ? Wq : ((nt == 1) ? Wk : Wv);
    const int tid = threadIdx.x;
#pragma unroll
    for (int j = 0; j < 32; ++j) {
        int idx = tid + j * 256;
        int k = idx >> 7, n = idx & 127;
        tile[k][n] = bfbits(src[(size_t)(k0 + k) * HS + n]);
    }
    __syncthreads();
#pragma unroll
    for (int j = 0; j < 32; ++j) {
        int idx = tid + j * 256;
        int n = idx >> 6, kk = idx & 63;
        Wt[(size_t)(nt * 128 + n) * N_EMBD + k0 + kk] = tile[kk][n];
    }
}

// ---------------- Kernel 1: fully fused head, one block per batch ----------------
// 256 blocks x 512 threads (8 waves), 1 block/CU. LDS 139264 B, two overlaid eras:
//   K-loop era (double-buffered staging, BK=64, ONE barrier per step):
//     A dbuf [2][128 rows][144 B]  @ 0      (bf16, +16 B row pad)
//     B dbuf [2][384 rows][128 B]  @ 36864  (bf16, XOR-swizzled 16B granules)
//   post-loop era (after final barrier):
//     QS/KS @ 0/34816 (q,k bf16 [t][d], 272 B rows), VS @ 69632 ([d][s]),
//     PST  @ 104448 (phase-2 P staging, 8 waves x 16 rows x 272 B)
// Pipeline per step t: issue A(t+1) global->regs + B(t+1) async16 into buf^1;
// compute step t (20 ds_read_b128 + 48 MFMA) from buf; cvt+ds_write A(t+1);
// __syncthreads (its vmcnt(0)/lgkmcnt(0) drain is covered by the compute phase).
__global__ __launch_bounds__(512, 2) void head_fused(
    const float* __restrict__ x,
    const unsigned short* __restrict__ Wt,
    float* __restrict__ out)
{
    __shared__ char lds[139264];
    constexpr int AST = 0,     ASZ = 18432;   // A staging buffers
    constexpr int BST = 36864, BSZ = 49152;   // B staging buffers
    constexpr int QS  = 0;
    constexpr int KS  = 34816;
    constexpr int VS  = 69632;
    constexpr int PST = 104448;

    const int tid  = threadIdx.x;
    const int w    = tid >> 6;
    const int l    = tid & 63;
    const int cl   = l & 15;
    const int quad = l >> 4;
    const int b    = blockIdx.x;
    const int row0 = b << 7;
    const int wm   = (w & 1) << 6;     // 0 or 64
    const int wn   = (w >> 1) * 96;    // 0,96,192,288

    // ---- phase 1: QKV GEMM, BK=64, 16 steps ----
    // A staging map: 8 threads/row, 8 f32 each, row groups (tid>>3) and +64.
    const int ar = tid >> 3;           // 0..63
    const int ac = (tid & 7) << 3;     // f32 col 0..56
    const float* aptr = x + (size_t)row0 * N_EMBD;
    // B staging: lane l of async16 j writes phys granule (l&7) of row (l>>3);
    // pre-swizzle the SOURCE so logical granule g sits at phys g^(row&7).
    const int brow = l >> 3;                 // row within 8-row group
    const int bxo  = ((l & 7) ^ brow) << 3;  // source element offset (x8 bf16)

    f32x4 acc[4][6];
#pragma unroll
    for (int a = 0; a < 4; ++a)
#pragma unroll
        for (int c = 0; c < 6; ++c) acc[a][c] = zero4();

    // prologue: stage chunk 0 into buf 0
    {
#pragma unroll
        for (int jj = 0; jj < 6; ++jj) {
            int n = w * 48 + jj * 8 + brow;
            async16(Wt + (size_t)n * N_EMBD + bxo,
                    lds + BST + (w * 6 + jj) * 1024);
        }
        f32x4 p0[2], p1[2];
#pragma unroll
        for (int rr = 0; rr < 2; ++rr) {
            const float* p = aptr + (size_t)(ar + rr * 64) * N_EMBD + ac;
            p0[rr] = *(const f32x4*)p;
            p1[rr] = *(const f32x4*)(p + 4);
        }
#pragma unroll
        for (int rr = 0; rr < 2; ++rr) {
            bf16x8 aw;
            aw[0] = (__bf16)p0[rr][0]; aw[1] = (__bf16)p0[rr][1];
            aw[2] = (__bf16)p0[rr][2]; aw[3] = (__bf16)p0[rr][3];
            aw[4] = (__bf16)p1[rr][0]; aw[5] = (__bf16)p1[rr][1];
            aw[6] = (__bf16)p1[rr][2]; aw[7] = (__bf16)p1[rr][3];
            *(bf16x8*)(lds + AST + (ar + rr * 64) * 144 + ac * 2) = aw;
        }
        __syncthreads();
    }

    int cur = 0;
#pragma unroll 2
    for (int t = 0; t < 16; ++t) {
        const int kc = (t + 1) << 6;
        f32x4 p0[2], p1[2];
        if (t < 15) {
            // A prefetch for t+1 (global -> regs); issued first: max latency window
#pragma unroll
            for (int rr = 0; rr < 2; ++rr) {
                const float* p = aptr + (size_t)(ar + rr * 64) * N_EMBD + kc + ac;
                p0[rr] = *(const f32x4*)p;
                p1[rr] = *(const f32x4*)(p + 4);
            }
            // B prefetch for t+1 straight into the other LDS buffer
#pragma unroll
            for (int jj = 0; jj < 6; ++jj) {
                int n = w * 48 + jj * 8 + brow;
                async16(Wt + (size_t)n * N_EMBD + kc + bxo,
                        lds + BST + (cur ^ 1) * BSZ + (w * 6 + jj) * 1024);
            }
        }
        // compute step t from buf[cur]
        const char* Ab = lds + AST + cur * ASZ;
        const char* Bb = lds + BST + cur * BSZ;
#pragma unroll
        for (int ks2 = 0; ks2 < 2; ++ks2) {
            bf16x8 af[4], bf[6];
#pragma unroll
            for (int rt = 0; rt < 4; ++rt)
                af[rt] = *(const bf16x8*)(Ab + (wm + rt * 16 + cl) * 144
                                          + ks2 * 64 + quad * 16);
#pragma unroll
            for (int ct = 0; ct < 6; ++ct) {
                int n = wn + ct * 16 + cl;
                bf[ct] = *(const bf16x8*)(Bb + n * 128
                                          + (((ks2 * 4 + quad) ^ (n & 7)) << 4));
            }
#pragma unroll
            for (int rt = 0; rt < 4; ++rt)
#pragma unroll
                for (int ct = 0; ct < 6; ++ct)
                    acc[rt][ct] = __builtin_amdgcn_mfma_f32_16x16x32_bf16(
                        af[rt], bf[ct], acc[rt][ct], 0, 0, 0);
        }
        if (t < 15) {
            // keep the A-reg use (and its implicit vmcnt wait) AFTER the MFMAs
            __builtin_amdgcn_sched_barrier(0);
            char* An = lds + AST + (cur ^ 1) * ASZ;
#pragma unroll
            for (int rr = 0; rr < 2; ++rr) {
                bf16x8 aw;
                aw[0] = (__bf16)p0[rr][0]; aw[1] = (__bf16)p0[rr][1];
                aw[2] = (__bf16)p0[rr][2]; aw[3] = (__bf16)p0[rr][3];
                aw[4] = (__bf16)p1[rr][0]; aw[5] = (__bf16)p1[rr][1];
                aw[6] = (__bf16)p1[rr][2]; aw[7] = (__bf16)p1[rr][3];
                *(bf16x8*)(An + (ar + rr * 64) * 144 + ac * 2) = aw;
            }
        }
        __syncthreads();   // single barrier per step; vmcnt drain ~free here
        cur ^= 1;
    }

    // ---- epilogue: RoPE + q/k/v -> LDS (staging region is dead from here on) ----
    const float LNT = 0.07195578430905272f;   // ln(10000)/128
#pragma unroll
    for (int ct = 0; ct < 6; ++ct) {
        int c0  = wn + ct * 16;
        int ntc = c0 >> 7;                    // 0=q 1=k 2=v, uniform per tile
        int d   = (c0 & 127) + cl;
        if (ntc < 2) {
            int qk = (ntc == 0) ? QS : KS;
            float freq = __expf(-(float)(d & ~1) * LNT);
#pragma unroll
            for (int rt = 0; rt < 4; ++rt) {
#pragma unroll
                for (int i = 0; i < 4; ++i) {
                    int t = wm + rt * 16 + quad * 4 + i;   // position in batch
                    float v = acc[rt][ct][i];
                    float p = __shfl_xor(v, 1);
                    float sn, cs;
                    __sincosf((float)t * freq, &sn, &cs);
                    float r = ((d & 1) == 0) ? (v * cs - p * sn) : (p * sn + v * cs);
                    *(unsigned short*)(lds + qk + t * 272 + d * 2) = bfbits(r);
                }
            }
        } else {
            // v: LDS [d][s], 4 consecutive s -> one 8 B write
#pragma unroll
            for (int rt = 0; rt < 4; ++rt) {
                int s0 = wm + rt * 16 + quad * 4;
                us4 u;
                u.x = bfbits(acc[rt][ct][0]);
                u.y = bfbits(acc[rt][ct][1]);
                u.z = bfbits(acc[rt][ct][2]);
                u.w = bfbits(acc[rt][ct][3]);
                *(us4*)(lds + VS + d * 272 + s0 * 2) = u;
            }
        }
    }
    __syncthreads();   // q/k/v visible to all waves

    // ---- phase 2: causal attention, wave w owns Q rows [w*16, w*16+16) ----
    const int nct = w + 1;
    const int nks = (w + 2) >> 1;
    char* pl = lds + PST + w * 4352;   // 16 rows x 272 B per wave

    bf16x8 qf[4];
#pragma unroll
    for (int ks = 0; ks < 4; ++ks)
        qf[ks] = *(const bf16x8*)(lds + QS + (w * 16 + cl) * 272 + (ks * 4 + quad) * 16);

    f32x4 s[8];
#pragma unroll
    for (int ct = 0; ct < 8; ++ct) s[ct] = zero4();

#pragma unroll
    for (int ct = 0; ct < 8; ++ct) if (ct < nct) {
        const char* kr = lds + KS + (ct * 16 + cl) * 272;
#pragma unroll
        for (int ks = 0; ks < 4; ++ks) {
            bf16x8 bb = *(const bf16x8*)(kr + (ks * 4 + quad) * 16);
            s[ct] = __builtin_amdgcn_mfma_f32_16x16x32_bf16(qf[ks], bb, s[ct], 0, 0, 0);
        }
    }

    const float scale = 0.08838834764831845f;   // 1/sqrt(128)
#pragma unroll
    for (int i = 0; i < 4; ++i) {
        int t = w * 16 + quad * 4 + i;
        float mx = -3.0e38f;
#pragma unroll
        for (int ct = 0; ct < 8; ++ct) if (ct < nct) {
            int col = ct * 16 + cl;
            float v = s[ct][i] * scale;
            v = (col <= t) ? v : -INFINITY;
            s[ct][i] = v;
            mx = fmaxf(mx, v);
        }
        mx = fmaxf(mx, __shfl_xor(mx, 1));
        mx = fmaxf(mx, __shfl_xor(mx, 2));
        mx = fmaxf(mx, __shfl_xor(mx, 4));
        mx = fmaxf(mx, __shfl_xor(mx, 8));
        float sum = 0.f;
#pragma unroll
        for (int ct = 0; ct < 8; ++ct) if (ct < nct) {
            float p = __expf(s[ct][i] - mx);
            s[ct][i] = p;
            sum += p;
        }
        sum += __shfl_xor(sum, 1);
        sum += __shfl_xor(sum, 2);
        sum += __shfl_xor(sum, 4);
        sum += __shfl_xor(sum, 8);
        float inv = 1.0f / sum;
        int rl = quad * 4 + i;
#pragma unroll
        for (int ct = 0; ct < 8; ++ct) if (ct < nct) {
            *(unsigned short*)(pl + rl * 272 + (ct * 16 + cl) * 2) =
                bfbits(s[ct][i] * inv);
        }
        if ((w & 1) == 0) {   // PV consumes one 16-col tile past the stored range
            *(unsigned short*)(pl + rl * 272 + (nct * 16 + cl) * 2) = 0;
        }
    }
    // same-wave ds_write -> ds_read: compiler inserts lgkmcnt wait; no barrier.

    bf16x8 ap[4];
#pragma unroll
    for (int ks = 0; ks < 4; ++ks) if (ks < nks)
        ap[ks] = *(const bf16x8*)(pl + cl * 272 + (ks * 4 + quad) * 16);

    f32x4 o[8];
#pragma unroll
    for (int ct = 0; ct < 8; ++ct) o[ct] = zero4();

#pragma unroll
    for (int ct = 0; ct < 8; ++ct) {
        const char* vr = lds + VS + (ct * 16 + cl) * 272;
#pragma unroll
        for (int ks = 0; ks < 4; ++ks) if (ks < nks) {
            bf16x8 bb = *(const bf16x8*)(vr + (ks * 4 + quad) * 16);
            o[ct] = __builtin_amdgcn_mfma_f32_16x16x32_bf16(ap[ks], bb, o[ct], 0, 0, 0);
        }
    }

#pragma unroll
    for (int ct = 0; ct < 8; ++ct)
#pragma unroll
        for (int i = 0; i < 4; ++i) {
            int t = w * 16 + quad * 4 + i;
            out[(size_t)b * 16384 + (size_t)t * HS + ct * 16 + cl] = o[ct][i];
        }
}

// ---------------- launch ----------------
extern "C" void kernel_launch(void* const* d_in, const int* in_sizes, int n_in,
                              void* d_out, int out_size, void* d_ws, size_t ws_size,
                              hipStream_t stream) {
    const float* x  = (const float*)d_in[0];
    const float* Wq = (const float*)d_in[1];
    const float* Wk = (const float*)d_in[2];
    const float* Wv = (const float*)d_in[3];
    float* out = (float*)d_out;

    unsigned short* Wt = (unsigned short*)d_ws;   // 384 x 1024 bf16 = 768 KB

    wcast<<<48, 256, 0, stream>>>(Wq, Wk, Wv, Wt);
    head_fused<<<BATCH, 512, 0, stream>>>(x, Wt, out);
}